// Round 15
// baseline (204.076 us; speedup 1.0000x reference)
//
#include <hip/hip_runtime.h>
#include <hip/hip_bf16.h>

typedef short bf16x8 __attribute__((ext_vector_type(8)));
typedef float f32x4 __attribute__((ext_vector_type(4)));
typedef unsigned short us4v __attribute__((ext_vector_type(4)));
typedef unsigned int uint2v __attribute__((ext_vector_type(2)));

#define DEV static __device__ __forceinline__

DEV float bf2f(unsigned short u){ unsigned int x = ((unsigned int)u)<<16; float f; __builtin_memcpy(&f,&x,4); return f; }
DEV unsigned short f2bf(float f){ unsigned int x; __builtin_memcpy(&x,&f,4); x = (x + 0x7fffu + ((x>>16)&1u)) >> 16; return (unsigned short)x; }

// truncation pack: bf16(lo) | bf16(hi)<<16 (round-toward-zero), 1 VALU op.
#if __has_builtin(__builtin_amdgcn_perm)
DEV unsigned int pack_trunc(float lo, float hi){
  unsigned int a, b;
  __builtin_memcpy(&a, &lo, 4);
  __builtin_memcpy(&b, &hi, 4);
  return __builtin_amdgcn_perm(b, a, 0x07060302u);  // [hi.b3,hi.b2,lo.b3,lo.b2]
}
#else
DEV unsigned int pack_trunc(float lo, float hi){
  unsigned int a, b;
  __builtin_memcpy(&a, &lo, 4);
  __builtin_memcpy(&b, &hi, 4);
  return (b & 0xffff0000u) | (a >> 16);
}
#endif

DEV void stor(unsigned short* p, float v){ *p = f2bf(v); }
DEV void stor(float* p, float v){ *p = v; }

#if __has_builtin(__builtin_amdgcn_exp2f)
DEV float fexp2(float x){ return __builtin_amdgcn_exp2f(x); }   // bare v_exp_f32; |x|<=~12 here
#else
DEV float fexp2(float x){ return exp2f(x); }
#endif

#if __has_builtin(__builtin_amdgcn_permlane32_swap)
DEV uint2v pl32(unsigned int a, unsigned int b){ return __builtin_amdgcn_permlane32_swap(a, b, false, false); }
#else
DEV uint2v pl32(unsigned int a, unsigned int b){
  unsigned int sa = (unsigned int)__shfl_xor((int)a, 32);
  unsigned int sb = (unsigned int)__shfl_xor((int)b, 32);
  bool hi = (threadIdx.x & 32) != 0;
  uint2v r; r[0] = hi ? sb : a; r[1] = hi ? b : sa; return r;
}
#endif
#if __has_builtin(__builtin_amdgcn_permlane16_swap)
DEV uint2v pl16(unsigned int a, unsigned int b){ return __builtin_amdgcn_permlane16_swap(a, b, false, false); }
#else
DEV uint2v pl16(unsigned int a, unsigned int b){
  unsigned int sa = (unsigned int)__shfl_xor((int)a, 16);
  unsigned int sb = (unsigned int)__shfl_xor((int)b, 16);
  bool hi = (threadIdx.x & 16) != 0;
  uint2v r; r[0] = hi ? sb : a; r[1] = hi ? b : sa; return r;
}
#endif

#define GLOAD_LDS16(gptr, lptr) \
  __builtin_amdgcn_global_load_lds((__attribute__((address_space(1))) void*)(gptr), \
      (__attribute__((address_space(3))) void*)(lptr), 16, 0, 0)

// C = A[M,K] @ Bt[N,K]^T, bf16 inputs, OutT output. 128x128 tile, BK=32, 4 waves.
// (m97-structure: single LDS buffer, 2 barriers per K-step — proven)
template<typename OutT>
__global__ __launch_bounds__(256) void gemm_bt(
    const unsigned short* __restrict__ A,
    const unsigned short* __restrict__ Bt,
    OutT* __restrict__ C, int M, int N, int K)
{
  __shared__ unsigned short As[128*32];
  __shared__ unsigned short Bs[128*32];
  const int tid = threadIdx.x;
  const int w = tid>>6, l = tid&63, g = l>>4, q = l&15;
  const int m0 = blockIdx.x*128, n0 = blockIdx.y*128;
  f32x4 acc[4][4];
  const f32x4 fz = {0.f,0.f,0.f,0.f};
  for (int i=0;i<4;i++) for(int j=0;j<4;j++) acc[i][j] = fz;
  for (int k0 = 0; k0 < K; k0 += 32) {
    __syncthreads();
    #pragma unroll
    for (int r = 0; r < 2; ++r) {
      int p = r*4096 + tid*16;
      int row = p>>6, colb = p&63;
      const char* ga = (const char*)(A  + (size_t)(m0+row)*K + k0) + colb;
      const char* gb = (const char*)(Bt + (size_t)(n0+row)*K + k0) + colb;
      GLOAD_LDS16(ga, (char*)As + r*4096 + w*1024);
      GLOAD_LDS16(gb, (char*)Bs + r*4096 + w*1024);
    }
    __syncthreads();
    bf16x8 af[4], bfr[4];
    #pragma unroll
    for (int i=0;i<4;i++){
      af[i]  = *(const bf16x8*)&As[((w>>1)*64 + i*16 + q)*32 + g*8];
      bfr[i] = *(const bf16x8*)&Bs[((w&1)*64 + i*16 + q)*32 + g*8];
    }
    #pragma unroll
    for (int i=0;i<4;i++)
      #pragma unroll
      for (int j=0;j<4;j++)
        acc[i][j] = __builtin_amdgcn_mfma_f32_16x16x32_bf16(af[i], bfr[j], acc[i][j], 0,0,0);
  }
  #pragma unroll
  for (int i=0;i<4;i++)
    #pragma unroll
    for (int j=0;j<4;j++)
      #pragma unroll
      for (int v=0;v<4;v++){
        int row = m0 + (w>>1)*64 + i*16 + g*4 + v;
        int col = n0 + (w&1)*64 + j*16 + q;
        stor(&C[(size_t)row*N + col], acc[i][j][v]);
      }
}

// 256x256-tile gemm for the Q/K projection. 512 threads = 8 waves (2M x 4N),
// BK=64, static double-buffered LDS (128 KiB), one barrier per K-tile,
// global_load_lds staging with st_16x32-style swizzle (pre-swizzled source +
// swizzled ds_read: 16B-block j ^= ((row>>2)&1)<<1 within each 128B row).
__global__ __launch_bounds__(512,2) void gemm_qk(
    const unsigned short* __restrict__ A,
    const unsigned short* __restrict__ Bt,
    unsigned short* __restrict__ C, int M, int N, int K)
{
  __shared__ unsigned short As0[256*64], As1[256*64];  // 32 KiB each
  __shared__ unsigned short Bs0[256*64], Bs1[256*64];
  const int tid = threadIdx.x;
  const int w = tid>>6, l = tid&63, g = l>>4, q = l&15;
  const int wr = w>>2, wc = w&3;
  const int m0 = blockIdx.x*256, n0 = blockIdx.y*256;
  f32x4 acc[8][4];
  const f32x4 fz = {0.f,0.f,0.f,0.f};
  #pragma unroll
  for (int i=0;i<8;i++)
    #pragma unroll
    for (int j=0;j<4;j++) acc[i][j] = fz;

  // waves 0-3 stage A (64 rows each), waves 4-7 stage B. 8 x 1KB wave-instr.
  const bool isA = (w < 4);
  const int wrow0 = (w&3)*64;
  const unsigned short* gbase = isA ? A + (size_t)m0*K : Bt + (size_t)n0*K;

  auto STAGE = [&](unsigned short* Ad, unsigned short* Bd, int k0){
    unsigned short* dbase = isA ? Ad : Bd;
    #pragma unroll
    for (int n=0;n<8;n++){
      int row = wrow0 + n*8 + (l>>3);
      int jj = (l&7) ^ (((row>>2)&1)<<1);            // pre-swizzled source block
      const unsigned short* src = gbase + (size_t)row*K + k0 + jj*8;
      GLOAD_LDS16(src, (char*)dbase + (wrow0 + n*8)*128);  // wave-uniform base
    }
  };

  auto COMPUTE = [&](const unsigned short* Ar, const unsigned short* Br){
    const int jr = ((q>>2)&1)<<1;                    // read-side swizzle
    __builtin_amdgcn_s_setprio(1);
    #pragma unroll
    for (int kk=0;kk<2;kk++){
      bf16x8 af[8], bfv[4];
      int cb0 = ((kk*4+0) ^ jr)*16;
      int cb1 = ((kk*4+1) ^ jr)*16;
      int cb2 = ((kk*4+2) ^ jr)*16;
      int cb3 = ((kk*4+3) ^ jr)*16;
      int cb = (g==0)?cb0:(g==1)?cb1:(g==2)?cb2:cb3;   // = ((kk*4+g)^jr)*16
      #pragma unroll
      for (int i=0;i<8;i++)
        af[i] = *(const bf16x8*)((const char*)Ar + (wr*128 + i*16 + q)*128 + cb);
      #pragma unroll
      for (int j=0;j<4;j++)
        bfv[j] = *(const bf16x8*)((const char*)Br + (wc*64 + j*16 + q)*128 + cb);
      #pragma unroll
      for (int i=0;i<8;i++)
        #pragma unroll
        for (int j=0;j<4;j++)
          acc[i][j] = __builtin_amdgcn_mfma_f32_16x16x32_bf16(af[i], bfv[j], acc[i][j], 0,0,0);
    }
    __builtin_amdgcn_s_setprio(0);
  };

  STAGE(As0, Bs0, 0);
  __syncthreads();                       // tile 0 landed (vmcnt drain)
  for (int kt=0; kt<16; kt+=2){
    STAGE(As1, Bs1, (kt+1)*64);
    COMPUTE(As0, Bs0);
    __syncthreads();                     // As1/Bs1 ready; As0/Bs0 free
    if (kt+2 < 16) STAGE(As0, Bs0, (kt+2)*64);
    COMPUTE(As1, Bs1);
    if (kt+2 < 16) __syncthreads();      // As0/Bs0 ready; As1/Bs1 free
  }

  #pragma unroll
  for (int i=0;i<8;i++)
    #pragma unroll
    for (int j=0;j<4;j++)
      #pragma unroll
      for (int v=0;v<4;v++){
        int row = m0 + wr*128 + i*16 + g*4 + v;
        int col = n0 + wc*64 + j*16 + q;
        C[(size_t)row*N + col] = f2bf(acc[i][j][v]);
      }
}

// Wo projection with fused stream-combine: C = (A1 + A2) @ Bt^T, where
// A2 already holds -lambda * O2 (written by diff_attn). 64x128 tile.
__global__ __launch_bounds__(256) void gemm_wo_fused(
    const unsigned short* __restrict__ A1,
    const unsigned short* __restrict__ A2,
    const unsigned short* __restrict__ Bt,
    float* __restrict__ C, int M, int N, int K)
{
  __shared__ unsigned short As[64*32];    // 4 KiB
  __shared__ unsigned short Bs[128*32];   // 8 KiB
  const int tid = threadIdx.x;
  const int w = tid>>6, l = tid&63, g = l>>4, q = l&15;
  const int m0 = blockIdx.x*64, n0 = blockIdx.y*128;
  f32x4 acc[4][2];
  const f32x4 fz = {0.f,0.f,0.f,0.f};
  for (int i=0;i<4;i++) for(int j=0;j<2;j++) acc[i][j] = fz;
  for (int k0 = 0; k0 < K; k0 += 32) {
    __syncthreads();
    { // A: fused combine stage (reg roundtrip)
      int row = tid>>2, c8 = (tid&3)*8;
      const unsigned short* p1 = A1 + (size_t)(m0+row)*K + k0 + c8;
      const unsigned short* p2 = A2 + (size_t)(m0+row)*K + k0 + c8;
      bf16x8 v1 = *(const bf16x8*)p1;
      bf16x8 v2 = *(const bf16x8*)p2;
      bf16x8 o;
      #pragma unroll
      for (int e=0;e<8;e++)
        o[e] = (short)f2bf(bf2f((unsigned short)v1[e]) + bf2f((unsigned short)v2[e]));
      *(bf16x8*)&As[row*32 + c8] = o;
    }
    #pragma unroll
    for (int r = 0; r < 2; ++r) { // B: async
      int p = r*4096 + tid*16;
      int row = p>>6, colb = p&63;
      const char* gb = (const char*)(Bt + (size_t)(n0+row)*K + k0) + colb;
      GLOAD_LDS16(gb, (char*)Bs + r*4096 + w*1024);
    }
    __syncthreads();   // drains ds_writes (lgkmcnt) and gload_lds (vmcnt)
    bf16x8 af[4], bfr[2];
    #pragma unroll
    for (int i=0;i<4;i++) af[i] = *(const bf16x8*)&As[(i*16 + q)*32 + g*8];
    #pragma unroll
    for (int j=0;j<2;j++) bfr[j] = *(const bf16x8*)&Bs[(w*32 + j*16 + q)*32 + g*8];
    #pragma unroll
    for (int i=0;i<4;i++)
      #pragma unroll
      for (int j=0;j<2;j++)
        acc[i][j] = __builtin_amdgcn_mfma_f32_16x16x32_bf16(af[i], bfr[j], acc[i][j], 0,0,0);
  }
  #pragma unroll
  for (int i=0;i<4;i++)
    #pragma unroll
    for (int j=0;j<2;j++)
      #pragma unroll
      for (int v=0;v<4;v++){
        int row = m0 + i*16 + g*4 + v;
        int col = n0 + w*32 + j*16 + q;
        C[(size_t)row*N + col] = acc[i][j][v];
      }
}

// Differential flash attention v15: v14 core, LDQ = 4096 (QK-only buffer).
__global__ __launch_bounds__(256,4) void diff_attn(
    const unsigned short* __restrict__ Qp,
    const unsigned short* __restrict__ Kp,
    const unsigned short* __restrict__ Vt,
    const float* __restrict__ lambp,
    unsigned short* __restrict__ ao1,
    unsigned short* __restrict__ ao2)
{
  const int LDQ = 4096;
  __shared__ unsigned short Ks0[64*64];   // 8 KiB each, granule ^ (row&7)
  __shared__ unsigned short Ks1[64*64];
  __shared__ unsigned short Vs0[64*64];
  __shared__ unsigned short Vs1[64*64];
  const int tid = threadIdx.x, w = tid>>6, l = tid&63, g = l>>4, q = l&15;
  const int qb = blockIdx.x, h = blockIdx.y;
  const int s = blockIdx.z >> 1, b = blockIdx.z & 1;
  const int b2048 = b*2048;
  const int qrow0 = b2048 + qb*128 + w*32;
  const f32x4 fz = {0.f,0.f,0.f,0.f};
  const short one_bf = (short)0x3f80;
  const bf16x8 ones = {one_bf,one_bf,one_bf,one_bf,one_bf,one_bf,one_bf,one_bf};
  unsigned short* aout = s ? ao2 : ao1;

  // Q fragments for this stream (Q pre-scaled by 0.125*log2e via Wq)
  bf16x8 qf[2][2];
  #pragma unroll
  for (int qh=0; qh<2; ++qh){
    const unsigned short* qp = Qp + (size_t)(qrow0 + qh*16 + q)*LDQ + h*128 + s*64;
    #pragma unroll
    for (int kf=0;kf<2;kf++)
      qf[qh][kf] = *(const bf16x8*)(qp + kf*32 + g*8);
  }
  f32x4 acc[2][4];
  f32x4 acc_s[2];   // denominator via P @ ones
  #pragma unroll
  for (int qh=0;qh<2;qh++){
    acc_s[qh]=fz;
    #pragma unroll
    for (int i=0;i<4;i++) acc[qh][i]=fz;
  }

  // async staging: linear LDS dest, inverse-swizzled global src (rows = 128 B)
  auto STAGE = [&](unsigned short* Kd, unsigned short* Vd, int kt){
    #pragma unroll
    for (int ii=0; ii<2; ++ii){
      int krow = w*16 + ii*8 + (l>>3);
      int gr = (l&7) ^ (krow&7);
      const unsigned short* src = Kp + (size_t)(b2048 + kt + krow)*LDQ + h*128 + s*64 + gr*8;
      GLOAD_LDS16(src, (char*)Kd + (w*16 + ii*8)*128);
    }
    #pragma unroll
    for (int jj=0; jj<2; ++jj){
      int vrow = w*16 + jj*8 + (l>>3);
      int gr = (l&7) ^ (vrow&7);
      const unsigned short* src = Vt + (size_t)(h*64 + vrow)*4096 + b2048 + kt + gr*8;
      GLOAD_LDS16(src, (char*)Vd + (w*16 + jj*8)*128);
    }
  };

  auto COMPUTE = [&](const unsigned short* Kr, const unsigned short* Vr){
    const int sw = q & 7;
    // ---- swapped QK^T (this stream): z[fn] = C[key=fn*16+g*4+i][qrow] ----
    unsigned int cc[2][4][2];
    #pragma unroll
    for (int fn=0; fn<4; ++fn) {
      const unsigned short* kr = Kr + (fn*16 + q)*64;
      bf16x8 kb0 = *(const bf16x8*)&kr[((0+g)^sw)*8];
      bf16x8 kb1 = *(const bf16x8*)&kr[((4+g)^sw)*8];
      f32x4 z[2];
      __builtin_amdgcn_s_setprio(1);
      #pragma unroll
      for (int qh=0; qh<2; ++qh){
        f32x4 a = fz;
        a = __builtin_amdgcn_mfma_f32_16x16x32_bf16(kb0, qf[qh][0], a, 0,0,0);
        a = __builtin_amdgcn_mfma_f32_16x16x32_bf16(kb1, qf[qh][1], a, 0,0,0);
        z[qh] = a;
      }
      __builtin_amdgcn_s_setprio(0);
      #pragma unroll
      for (int qh=0; qh<2; ++qh){
        cc[qh][fn][0] = pack_trunc(fexp2(z[qh][0]), fexp2(z[qh][1]));
        cc[qh][fn][1] = pack_trunc(fexp2(z[qh][2]), fexp2(z[qh][3]));
      }
    }

    // ---- in-register P -> A-frag via permlane swaps ----
    bf16x8 pa[2][2];
    #pragma unroll
    for (int qh=0; qh<2; ++qh)
      #pragma unroll
      for (int kh=0; kh<2; ++kh){
        unsigned int* u = (unsigned int*)&pa[qh][kh];
        #pragma unroll
        for (int j=0;j<2;j++){
          uint2v d = pl32(cc[qh][2*kh][j], cc[qh][2*kh+1][j]);
          uint2v e = pl16(d[0], d[1]);
          u[j] = e[0]; u[2+j] = e[1];
        }
      }

    // ---- PV + denominator MFMAs ----
    __builtin_amdgcn_s_setprio(1);
    #pragma unroll
    for (int kh=0; kh<2; ++kh){
      #pragma unroll
      for (int qh=0; qh<2; ++qh)
        acc_s[qh] = __builtin_amdgcn_mfma_f32_16x16x32_bf16(pa[qh][kh], ones, acc_s[qh], 0,0,0);
      #pragma unroll
      for (int fd=0; fd<4; ++fd){
        bf16x8 vb = *(const bf16x8*)&Vr[(fd*16+q)*64 + ((kh*4+g)^sw)*8];
        #pragma unroll
        for (int qh=0; qh<2; ++qh)
          acc[qh][fd] = __builtin_amdgcn_mfma_f32_16x16x32_bf16(pa[qh][kh], vb, acc[qh][fd], 0,0,0);
      }
    }
    __builtin_amdgcn_s_setprio(0);
  };

  STAGE(Ks0, Vs0, 0);
  __syncthreads();   // tile 0 landed

  for (int t=0; t<32; t+=2) {
    STAGE(Ks1, Vs1, (t+1)*64);        // tiles 1..31, always valid
    COMPUTE(Ks0, Vs0);
    __syncthreads();                  // Ks1/Vs1 ready; Ks0/Vs0 free
    if (t+2 < 32) STAGE(Ks0, Vs0, (t+2)*64);
    COMPUTE(Ks1, Vs1);
    if (t+2 < 32) __syncthreads();    // Ks0/Vs0 ready; Ks1/Vs1 free
  }

  // epilogue: per-stream normalized output; stream 1 pre-multiplied by -lambda
  float sgn = s ? -lambp[0] : 1.0f;
  #pragma unroll
  for (int qh=0; qh<2; ++qh){
    float inv[4];
    #pragma unroll
    for (int i=0;i<4;i++) inv[i] = sgn/acc_s[qh][i];
    #pragma unroll
    for (int fd=0; fd<4; ++fd)
      #pragma unroll
      for (int i=0;i<4;i++){
        int row = qrow0 + qh*16 + g*4 + i;
        int col = h*64 + fd*16 + q;
        aout[(size_t)row*1024 + col] = f2bf(acc[qh][fd][i]*inv[i]);
      }
  }
}

// Fused prep: [0,4096) x->bf16 | [4096,10240) weight transposes | 10240 lambda.
__global__ __launch_bounds__(256) void prep_k(
    const float* __restrict__ x, unsigned short* __restrict__ xb,
    const float* __restrict__ Wq, const float* __restrict__ Wk,
    const float* __restrict__ Wv, const float* __restrict__ Wo,
    unsigned short* __restrict__ WcatT, unsigned short* __restrict__ WoT,
    float qscale,
    const float* __restrict__ lq1, const float* __restrict__ lk1,
    const float* __restrict__ lq2, const float* __restrict__ lk2,
    float* __restrict__ lambp)
{
  int bid = blockIdx.x;
  int tid = threadIdx.x;
  if (bid < 4096){
    int i = (bid*256 + tid)*4;
    float4 vv = *(const float4*)(x + i);
    us4v o; o[0]=f2bf(vv.x); o[1]=f2bf(vv.y); o[2]=f2bf(vv.z); o[3]=f2bf(vv.w);
    *(us4v*)(xb + i) = o;
    return;
  }
  if (bid < 10240){
    __shared__ unsigned short t[32][33];
    int wb = bid - 4096;
    const float* in; unsigned short* out; int C; float scale = 1.0f;
    if (wb < 2048){ in = Wq; out = WcatT;             C = 2048; scale = qscale; }
    else if (wb < 4096){ in = Wk; out = WcatT + 2048*1024; C = 2048; wb -= 2048; }
    else if (wb < 5120){ in = Wv; out = WcatT + 4096*1024; C = 1024; wb -= 4096; }
    else { in = Wo; out = WoT; C = 1024; wb -= 5120; }
    int xt = (C == 2048) ? (wb & 63) : (wb & 31);
    int yt = (C == 2048) ? (wb >> 6) : (wb >> 5);
    int c0 = xt*32, r0 = yt*32;
    int xx = tid & 31, yy = tid >> 5;
    #pragma unroll
    for (int d=0; d<32; d+=8) t[yy+d][xx] = f2bf(in[(size_t)(r0+yy+d)*C + c0 + xx] * scale);
    __syncthreads();
    #pragma unroll
    for (int d=0; d<32; d+=8) out[(size_t)(c0+yy+d)*1024 + r0 + xx] = t[xx][yy+d];
    return;
  }
  { // lambda
    int i = tid & 63;
    float a = lq1[i]*lk1[i], c = lq2[i]*lk2[i];
    #pragma unroll
    for (int o=32;o>0;o>>=1){ a += __shfl_down(a,o); c += __shfl_down(c,o); }
    if (tid==0) lambp[0] = expf(a) - expf(c) + 0.7778700995592560f; // LAMBDA_INIT layer 12
  }
}

// in: [R][C] bf16 (row stride ldin) -> out: [C][R] bf16
__global__ void transpose_bf16_ld(const unsigned short* __restrict__ in, unsigned short* __restrict__ out, int R, int C, int ldin){
  __shared__ unsigned short t[32][33];
  int c0 = blockIdx.x*32, r0 = blockIdx.y*32;
  int x = threadIdx.x, y = threadIdx.y;
  #pragma unroll
  for (int d=0; d<32; d+=8) t[y+d][x] = in[(size_t)(r0+y+d)*ldin + c0 + x];
  __syncthreads();
  #pragma unroll
  for (int d=0; d<32; d+=8) out[(size_t)(c0+y+d)*R + r0 + x] = t[x][y+d];
}

__global__ __launch_bounds__(256) void ln_k(const float* __restrict__ in, const float* __restrict__ gam,
                                            const float* __restrict__ bet, float* __restrict__ out){
  int row = blockIdx.x, t = threadIdx.x;
  const float4* rp = (const float4*)(in + (size_t)row*1024);
  float4 v4 = rp[t];
  float s = v4.x+v4.y+v4.z+v4.w;
  float ss = v4.x*v4.x+v4.y*v4.y+v4.z*v4.z+v4.w*v4.w;
  #pragma unroll
  for (int o=1;o<64;o<<=1){ s += __shfl_xor(s,o); ss += __shfl_xor(ss,o); }
  __shared__ float red[8];
  int w = t>>6, l = t&63;
  if (l==0){ red[w]=s; red[4+w]=ss; }
  __syncthreads();
  s = red[0]+red[1]+red[2]+red[3];
  ss = red[4]+red[5]+red[6]+red[7];
  float mean = s*(1.0f/1024.0f);
  float var = ss*(1.0f/1024.0f) - mean*mean;
  float rstd = rsqrtf(var + 1e-5f);
  float4 gv = ((const float4*)gam)[t], bv = ((const float4*)bet)[t];
  float4 o;
  o.x = (v4.x-mean)*rstd*gv.x + bv.x;
  o.y = (v4.y-mean)*rstd*gv.y + bv.y;
  o.z = (v4.z-mean)*rstd*gv.z + bv.z;
  o.w = (v4.w-mean)*rstd*gv.w + bv.w;
  ((float4*)(out + (size_t)row*1024))[t] = o;
}

extern "C" void kernel_launch(void* const* d_in, const int* in_sizes, int n_in,
                              void* d_out, int out_size, void* d_ws, size_t ws_size,
                              hipStream_t stream) {
  const float* x     = (const float*)d_in[0];
  const float* Wq    = (const float*)d_in[1];
  const float* Wk    = (const float*)d_in[2];
  const float* Wv    = (const float*)d_in[3];
  const float* Wo    = (const float*)d_in[4];
  const float* lq1   = (const float*)d_in[5];
  const float* lk1   = (const float*)d_in[6];
  const float* lq2   = (const float*)d_in[7];
  const float* lk2   = (const float*)d_in[8];
  const float* gamma = (const float*)d_in[9];
  const float* beta  = (const float*)d_in[10];
  float* out = (float*)d_out;

  char* ws = (char*)d_ws;
  unsigned short* xb    = (unsigned short*)(ws);                   //  8,388,608 B
  unsigned short* WcatT = (unsigned short*)(ws + 8388608);         // 10,485,760  [5120][1024] (QK rows 0..4095, V rows 4096..5119)
  unsigned short* WoT   = (unsigned short*)(ws + 18874368);        //  2,097,152
  unsigned short* QK    = (unsigned short*)(ws + 20971520);        // 33,554,432  [4096][4096]
  unsigned short* Vb    = (unsigned short*)(ws + 54525952);        //  8,388,608  [4096][1024]
  unsigned short* Vtb   = (unsigned short*)(ws + 62914560);        //  8,388,608  [1024][4096]
  unsigned short* AO1   = (unsigned short*)(ws + 71303168);        //  8,388,608
  unsigned short* AO2   = (unsigned short*)(ws + 79691776);        //  8,388,608
  float*          proj  = (float*)(ws + 20971520);                 // aliases QK (dead after diff_attn)
  float*          lambp = (float*)(ws + 96468992);                 //  4

  const float QSCALE = 0.125f * 1.4426950408889634f;  // folded into Wq
  dim3 tb(32,8);
  prep_k<<<10241, 256, 0, stream>>>(x, xb, Wq, Wk, Wv, Wo, WcatT, WoT, QSCALE,
                                    lq1, lk1, lq2, lk2, lambp);

  // Q|K projection: [4096][1024] @ [4096][1024]^T -> [4096][4096], 256^2 tiles
  gemm_qk<<<dim3(16,16), 512, 0, stream>>>(xb, WcatT, QK, 4096, 4096, 1024);
  // V projection: [4096][1024] @ [1024][1024]^T -> [4096][1024], 128^2 tiles
  gemm_bt<unsigned short><<<dim3(32,8), 256, 0, stream>>>(xb, WcatT + 4096*1024, Vb, 4096, 1024, 1024);
  // V^T
  transpose_bf16_ld<<<dim3(32,128), tb, 0, stream>>>(Vb, Vtb, 4096, 1024, 1024);

  // stream-split attention: z = s*2 + b; stream 1 writes -lambda * O2
  diff_attn<<<dim3(16,16,4), 256, 0, stream>>>(QK, QK + 2048, Vtb, lambp, AO1, AO2);

  // Wo projection with fused combine: (AO1 + AO2) @ WoT
  gemm_wo_fused<<<dim3(64,8), 256, 0, stream>>>(AO1, AO2, WoT, proj, 4096, 1024, 1024);
  ln_k<<<4096, 256, 0, stream>>>(proj, gamma, beta, out);
}

// Round 16
// 190.864 us; speedup vs baseline: 1.0692x; 1.0692x over previous
//
#include <hip/hip_runtime.h>
#include <hip/hip_bf16.h>

typedef short bf16x8 __attribute__((ext_vector_type(8)));
typedef float f32x4 __attribute__((ext_vector_type(4)));
typedef unsigned short us4v __attribute__((ext_vector_type(4)));
typedef unsigned int uint2v __attribute__((ext_vector_type(2)));

#define DEV static __device__ __forceinline__

DEV float bf2f(unsigned short u){ unsigned int x = ((unsigned int)u)<<16; float f; __builtin_memcpy(&f,&x,4); return f; }
DEV unsigned short f2bf(float f){ unsigned int x; __builtin_memcpy(&x,&f,4); x = (x + 0x7fffu + ((x>>16)&1u)) >> 16; return (unsigned short)x; }

// truncation pack: bf16(lo) | bf16(hi)<<16 (round-toward-zero), 1 VALU op.
#if __has_builtin(__builtin_amdgcn_perm)
DEV unsigned int pack_trunc(float lo, float hi){
  unsigned int a, b;
  __builtin_memcpy(&a, &lo, 4);
  __builtin_memcpy(&b, &hi, 4);
  return __builtin_amdgcn_perm(b, a, 0x07060302u);  // [hi.b3,hi.b2,lo.b3,lo.b2]
}
#else
DEV unsigned int pack_trunc(float lo, float hi){
  unsigned int a, b;
  __builtin_memcpy(&a, &lo, 4);
  __builtin_memcpy(&b, &hi, 4);
  return (b & 0xffff0000u) | (a >> 16);
}
#endif

#if __has_builtin(__builtin_amdgcn_exp2f)
DEV float fexp2(float x){ return __builtin_amdgcn_exp2f(x); }   // bare v_exp_f32; |x|<=~12 here
#else
DEV float fexp2(float x){ return exp2f(x); }
#endif

#if __has_builtin(__builtin_amdgcn_permlane32_swap)
DEV uint2v pl32(unsigned int a, unsigned int b){ return __builtin_amdgcn_permlane32_swap(a, b, false, false); }
#else
DEV uint2v pl32(unsigned int a, unsigned int b){
  unsigned int sa = (unsigned int)__shfl_xor((int)a, 32);
  unsigned int sb = (unsigned int)__shfl_xor((int)b, 32);
  bool hi = (threadIdx.x & 32) != 0;
  uint2v r; r[0] = hi ? sb : a; r[1] = hi ? b : sa; return r;
}
#endif
#if __has_builtin(__builtin_amdgcn_permlane16_swap)
DEV uint2v pl16(unsigned int a, unsigned int b){ return __builtin_amdgcn_permlane16_swap(a, b, false, false); }
#else
DEV uint2v pl16(unsigned int a, unsigned int b){
  unsigned int sa = (unsigned int)__shfl_xor((int)a, 16);
  unsigned int sb = (unsigned int)__shfl_xor((int)b, 16);
  bool hi = (threadIdx.x & 16) != 0;
  uint2v r; r[0] = hi ? sb : a; r[1] = hi ? b : sa; return r;
}
#endif

#define GLOAD_LDS16(gptr, lptr) \
  __builtin_amdgcn_global_load_lds((__attribute__((address_space(1))) void*)(gptr), \
      (__attribute__((address_space(3))) void*)(lptr), 16, 0, 0)

// Fused QKV projection: C = A[M,K] @ Bt[N,K]^T, N=5120. 128x128 tile, BK=32,
// 4 waves (m97-structure, proven). Q/K columns (n0<4096) are stored to
// QKV[row*5120+col]; V columns (n0>=4096) are stored TRANSPOSED to
// Vt[(col-4096)*4096 + row] (per lane: 4 consecutive token-rows = one 8B store)
// — this replaces the separate V-transpose kernel.
__global__ __launch_bounds__(256) void gemm_qkv(
    const unsigned short* __restrict__ A,
    const unsigned short* __restrict__ Bt,
    unsigned short* __restrict__ QKV,
    unsigned short* __restrict__ Vt,
    int M, int N, int K)
{
  __shared__ unsigned short As[128*32];
  __shared__ unsigned short Bs[128*32];
  const int tid = threadIdx.x;
  const int w = tid>>6, l = tid&63, g = l>>4, q = l&15;
  const int m0 = blockIdx.x*128, n0 = blockIdx.y*128;
  f32x4 acc[4][4];
  const f32x4 fz = {0.f,0.f,0.f,0.f};
  for (int i=0;i<4;i++) for(int j=0;j<4;j++) acc[i][j] = fz;
  for (int k0 = 0; k0 < K; k0 += 32) {
    __syncthreads();
    #pragma unroll
    for (int r = 0; r < 2; ++r) {
      int p = r*4096 + tid*16;
      int row = p>>6, colb = p&63;
      const char* ga = (const char*)(A  + (size_t)(m0+row)*K + k0) + colb;
      const char* gb = (const char*)(Bt + (size_t)(n0+row)*K + k0) + colb;
      GLOAD_LDS16(ga, (char*)As + r*4096 + w*1024);
      GLOAD_LDS16(gb, (char*)Bs + r*4096 + w*1024);
    }
    __syncthreads();
    bf16x8 af[4], bfr[4];
    #pragma unroll
    for (int i=0;i<4;i++){
      af[i]  = *(const bf16x8*)&As[((w>>1)*64 + i*16 + q)*32 + g*8];
      bfr[i] = *(const bf16x8*)&Bs[((w&1)*64 + i*16 + q)*32 + g*8];
    }
    #pragma unroll
    for (int i=0;i<4;i++)
      #pragma unroll
      for (int j=0;j<4;j++)
        acc[i][j] = __builtin_amdgcn_mfma_f32_16x16x32_bf16(af[i], bfr[j], acc[i][j], 0,0,0);
  }
  if (n0 < 4096){
    #pragma unroll
    for (int i=0;i<4;i++)
      #pragma unroll
      for (int j=0;j<4;j++)
        #pragma unroll
        for (int v=0;v<4;v++){
          int row = m0 + (w>>1)*64 + i*16 + g*4 + v;
          int col = n0 + (w&1)*64 + j*16 + q;
          QKV[(size_t)row*N + col] = f2bf(acc[i][j][v]);
        }
  } else {
    #pragma unroll
    for (int i=0;i<4;i++)
      #pragma unroll
      for (int j=0;j<4;j++){
        int vcol = n0 - 4096 + (w&1)*64 + j*16 + q;
        int row0 = m0 + (w>>1)*64 + i*16 + g*4;
        us4v o;
        #pragma unroll
        for (int v=0;v<4;v++) o[v] = f2bf(acc[i][j][v]);
        *(us4v*)&Vt[(size_t)vcol*4096 + row0] = o;
      }
  }
}

// Wo projection with fused stream-combine: C = (A1 + A2) @ Bt^T, where
// A2 already holds -lambda * O2 (written by diff_attn). 64x128 tile.
__global__ __launch_bounds__(256) void gemm_wo_fused(
    const unsigned short* __restrict__ A1,
    const unsigned short* __restrict__ A2,
    const unsigned short* __restrict__ Bt,
    float* __restrict__ C, int M, int N, int K)
{
  __shared__ unsigned short As[64*32];    // 4 KiB
  __shared__ unsigned short Bs[128*32];   // 8 KiB
  const int tid = threadIdx.x;
  const int w = tid>>6, l = tid&63, g = l>>4, q = l&15;
  const int m0 = blockIdx.x*64, n0 = blockIdx.y*128;
  f32x4 acc[4][2];
  const f32x4 fz = {0.f,0.f,0.f,0.f};
  for (int i=0;i<4;i++) for(int j=0;j<2;j++) acc[i][j] = fz;
  for (int k0 = 0; k0 < K; k0 += 32) {
    __syncthreads();
    { // A: fused combine stage (reg roundtrip)
      int row = tid>>2, c8 = (tid&3)*8;
      const unsigned short* p1 = A1 + (size_t)(m0+row)*K + k0 + c8;
      const unsigned short* p2 = A2 + (size_t)(m0+row)*K + k0 + c8;
      bf16x8 v1 = *(const bf16x8*)p1;
      bf16x8 v2 = *(const bf16x8*)p2;
      bf16x8 o;
      #pragma unroll
      for (int e=0;e<8;e++)
        o[e] = (short)f2bf(bf2f((unsigned short)v1[e]) + bf2f((unsigned short)v2[e]));
      *(bf16x8*)&As[row*32 + c8] = o;
    }
    #pragma unroll
    for (int r = 0; r < 2; ++r) { // B: async
      int p = r*4096 + tid*16;
      int row = p>>6, colb = p&63;
      const char* gb = (const char*)(Bt + (size_t)(n0+row)*K + k0) + colb;
      GLOAD_LDS16(gb, (char*)Bs + r*4096 + w*1024);
    }
    __syncthreads();   // drains ds_writes (lgkmcnt) and gload_lds (vmcnt)
    bf16x8 af[4], bfr[2];
    #pragma unroll
    for (int i=0;i<4;i++) af[i] = *(const bf16x8*)&As[(i*16 + q)*32 + g*8];
    #pragma unroll
    for (int j=0;j<2;j++) bfr[j] = *(const bf16x8*)&Bs[(w*32 + j*16 + q)*32 + g*8];
    #pragma unroll
    for (int i=0;i<4;i++)
      #pragma unroll
      for (int j=0;j<2;j++)
        acc[i][j] = __builtin_amdgcn_mfma_f32_16x16x32_bf16(af[i], bfr[j], acc[i][j], 0,0,0);
  }
  #pragma unroll
  for (int i=0;i<4;i++)
    #pragma unroll
    for (int j=0;j<2;j++)
      #pragma unroll
      for (int v=0;v<4;v++){
        int row = m0 + i*16 + g*4 + v;
        int col = n0 + w*32 + j*16 + q;
        C[(size_t)row*N + col] = acc[i][j][v];
      }
}

// Differential flash attention v16 (= round-14 v14, proven): stream-split,
// static dbuf, 1 barrier/tile, swapped QK^T, in-reg P, MFMA-ones denominators;
// s=1 stream writes -lambda * O2 (combine fused into gemm_wo_fused).
__global__ __launch_bounds__(256,4) void diff_attn(
    const unsigned short* __restrict__ Qp,
    const unsigned short* __restrict__ Kp,
    const unsigned short* __restrict__ Vt,
    const float* __restrict__ lambp,
    unsigned short* __restrict__ ao1,
    unsigned short* __restrict__ ao2)
{
  const int LDQ = 5120;
  __shared__ unsigned short Ks0[64*64];   // 8 KiB each, granule ^ (row&7)
  __shared__ unsigned short Ks1[64*64];
  __shared__ unsigned short Vs0[64*64];
  __shared__ unsigned short Vs1[64*64];
  const int tid = threadIdx.x, w = tid>>6, l = tid&63, g = l>>4, q = l&15;
  const int qb = blockIdx.x, h = blockIdx.y;
  const int s = blockIdx.z >> 1, b = blockIdx.z & 1;
  const int b2048 = b*2048;
  const int qrow0 = b2048 + qb*128 + w*32;
  const f32x4 fz = {0.f,0.f,0.f,0.f};
  const short one_bf = (short)0x3f80;
  const bf16x8 ones = {one_bf,one_bf,one_bf,one_bf,one_bf,one_bf,one_bf,one_bf};
  unsigned short* aout = s ? ao2 : ao1;

  // Q fragments for this stream (Q pre-scaled by 0.125*log2e via Wq)
  bf16x8 qf[2][2];
  #pragma unroll
  for (int qh=0; qh<2; ++qh){
    const unsigned short* qp = Qp + (size_t)(qrow0 + qh*16 + q)*LDQ + h*128 + s*64;
    #pragma unroll
    for (int kf=0;kf<2;kf++)
      qf[qh][kf] = *(const bf16x8*)(qp + kf*32 + g*8);
  }
  f32x4 acc[2][4];
  f32x4 acc_s[2];   // denominator via P @ ones
  #pragma unroll
  for (int qh=0;qh<2;qh++){
    acc_s[qh]=fz;
    #pragma unroll
    for (int i=0;i<4;i++) acc[qh][i]=fz;
  }

  // async staging: linear LDS dest, inverse-swizzled global src (rows = 128 B)
  auto STAGE = [&](unsigned short* Kd, unsigned short* Vd, int kt){
    #pragma unroll
    for (int ii=0; ii<2; ++ii){
      int krow = w*16 + ii*8 + (l>>3);
      int gr = (l&7) ^ (krow&7);
      const unsigned short* src = Kp + (size_t)(b2048 + kt + krow)*LDQ + h*128 + s*64 + gr*8;
      GLOAD_LDS16(src, (char*)Kd + (w*16 + ii*8)*128);
    }
    #pragma unroll
    for (int jj=0; jj<2; ++jj){
      int vrow = w*16 + jj*8 + (l>>3);
      int gr = (l&7) ^ (vrow&7);
      const unsigned short* src = Vt + (size_t)(h*64 + vrow)*4096 + b2048 + kt + gr*8;
      GLOAD_LDS16(src, (char*)Vd + (w*16 + jj*8)*128);
    }
  };

  auto COMPUTE = [&](const unsigned short* Kr, const unsigned short* Vr){
    const int sw = q & 7;
    // ---- swapped QK^T (this stream): z[fn] = C[key=fn*16+g*4+i][qrow] ----
    unsigned int cc[2][4][2];
    #pragma unroll
    for (int fn=0; fn<4; ++fn) {
      const unsigned short* kr = Kr + (fn*16 + q)*64;
      bf16x8 kb0 = *(const bf16x8*)&kr[((0+g)^sw)*8];
      bf16x8 kb1 = *(const bf16x8*)&kr[((4+g)^sw)*8];
      f32x4 z[2];
      __builtin_amdgcn_s_setprio(1);
      #pragma unroll
      for (int qh=0; qh<2; ++qh){
        f32x4 a = fz;
        a = __builtin_amdgcn_mfma_f32_16x16x32_bf16(kb0, qf[qh][0], a, 0,0,0);
        a = __builtin_amdgcn_mfma_f32_16x16x32_bf16(kb1, qf[qh][1], a, 0,0,0);
        z[qh] = a;
      }
      __builtin_amdgcn_s_setprio(0);
      #pragma unroll
      for (int qh=0; qh<2; ++qh){
        cc[qh][fn][0] = pack_trunc(fexp2(z[qh][0]), fexp2(z[qh][1]));
        cc[qh][fn][1] = pack_trunc(fexp2(z[qh][2]), fexp2(z[qh][3]));
      }
    }

    // ---- in-register P -> A-frag via permlane swaps ----
    bf16x8 pa[2][2];
    #pragma unroll
    for (int qh=0; qh<2; ++qh)
      #pragma unroll
      for (int kh=0; kh<2; ++kh){
        unsigned int* u = (unsigned int*)&pa[qh][kh];
        #pragma unroll
        for (int j=0;j<2;j++){
          uint2v d = pl32(cc[qh][2*kh][j], cc[qh][2*kh+1][j]);
          uint2v e = pl16(d[0], d[1]);
          u[j] = e[0]; u[2+j] = e[1];
        }
      }

    // ---- PV + denominator MFMAs ----
    __builtin_amdgcn_s_setprio(1);
    #pragma unroll
    for (int kh=0; kh<2; ++kh){
      #pragma unroll
      for (int qh=0; qh<2; ++qh)
        acc_s[qh] = __builtin_amdgcn_mfma_f32_16x16x32_bf16(pa[qh][kh], ones, acc_s[qh], 0,0,0);
      #pragma unroll
      for (int fd=0; fd<4; ++fd){
        bf16x8 vb = *(const bf16x8*)&Vr[(fd*16+q)*64 + ((kh*4+g)^sw)*8];
        #pragma unroll
        for (int qh=0; qh<2; ++qh)
          acc[qh][fd] = __builtin_amdgcn_mfma_f32_16x16x32_bf16(pa[qh][kh], vb, acc[qh][fd], 0,0,0);
      }
    }
    __builtin_amdgcn_s_setprio(0);
  };

  STAGE(Ks0, Vs0, 0);
  __syncthreads();   // tile 0 landed

  for (int t=0; t<32; t+=2) {
    STAGE(Ks1, Vs1, (t+1)*64);        // tiles 1..31, always valid
    COMPUTE(Ks0, Vs0);
    __syncthreads();                  // Ks1/Vs1 ready; Ks0/Vs0 free
    if (t+2 < 32) STAGE(Ks0, Vs0, (t+2)*64);
    COMPUTE(Ks1, Vs1);
    if (t+2 < 32) __syncthreads();    // Ks0/Vs0 ready; Ks1/Vs1 free
  }

  // epilogue: per-stream normalized output; stream 1 pre-multiplied by -lambda
  float sgn = s ? -lambp[0] : 1.0f;
  #pragma unroll
  for (int qh=0; qh<2; ++qh){
    float inv[4];
    #pragma unroll
    for (int i=0;i<4;i++) inv[i] = sgn/acc_s[qh][i];
    #pragma unroll
    for (int fd=0; fd<4; ++fd)
      #pragma unroll
      for (int i=0;i<4;i++){
        int row = qrow0 + qh*16 + g*4 + i;
        int col = h*64 + fd*16 + q;
        aout[(size_t)row*1024 + col] = f2bf(acc[qh][fd][i]*inv[i]);
      }
  }
}

// Fused prep: [0,4096) x->bf16 | [4096,10240) weight transposes | 10240 lambda.
__global__ __launch_bounds__(256) void prep_k(
    const float* __restrict__ x, unsigned short* __restrict__ xb,
    const float* __restrict__ Wq, const float* __restrict__ Wk,
    const float* __restrict__ Wv, const float* __restrict__ Wo,
    unsigned short* __restrict__ WcatT, unsigned short* __restrict__ WoT,
    float qscale,
    const float* __restrict__ lq1, const float* __restrict__ lk1,
    const float* __restrict__ lq2, const float* __restrict__ lk2,
    float* __restrict__ lambp)
{
  int bid = blockIdx.x;
  int tid = threadIdx.x;
  if (bid < 4096){
    int i = (bid*256 + tid)*4;
    float4 vv = *(const float4*)(x + i);
    us4v o; o[0]=f2bf(vv.x); o[1]=f2bf(vv.y); o[2]=f2bf(vv.z); o[3]=f2bf(vv.w);
    *(us4v*)(xb + i) = o;
    return;
  }
  if (bid < 10240){
    __shared__ unsigned short t[32][33];
    int wb = bid - 4096;
    const float* in; unsigned short* out; int C; float scale = 1.0f;
    if (wb < 2048){ in = Wq; out = WcatT;             C = 2048; scale = qscale; }
    else if (wb < 4096){ in = Wk; out = WcatT + 2048*1024; C = 2048; wb -= 2048; }
    else if (wb < 5120){ in = Wv; out = WcatT + 4096*1024; C = 1024; wb -= 4096; }
    else { in = Wo; out = WoT; C = 1024; wb -= 5120; }
    int xt = (C == 2048) ? (wb & 63) : (wb & 31);
    int yt = (C == 2048) ? (wb >> 6) : (wb >> 5);
    int c0 = xt*32, r0 = yt*32;
    int xx = tid & 31, yy = tid >> 5;
    #pragma unroll
    for (int d=0; d<32; d+=8) t[yy+d][xx] = f2bf(in[(size_t)(r0+yy+d)*C + c0 + xx] * scale);
    __syncthreads();
    #pragma unroll
    for (int d=0; d<32; d+=8) out[(size_t)(c0+yy+d)*1024 + r0 + xx] = t[xx][yy+d];
    return;
  }
  { // lambda
    int i = tid & 63;
    float a = lq1[i]*lk1[i], c = lq2[i]*lk2[i];
    #pragma unroll
    for (int o=32;o>0;o>>=1){ a += __shfl_down(a,o); c += __shfl_down(c,o); }
    if (tid==0) lambp[0] = expf(a) - expf(c) + 0.7778700995592560f; // LAMBDA_INIT layer 12
  }
}

__global__ __launch_bounds__(256) void ln_k(const float* __restrict__ in, const float* __restrict__ gam,
                                            const float* __restrict__ bet, float* __restrict__ out){
  int row = blockIdx.x, t = threadIdx.x;
  const float4* rp = (const float4*)(in + (size_t)row*1024);
  float4 v4 = rp[t];
  float s = v4.x+v4.y+v4.z+v4.w;
  float ss = v4.x*v4.x+v4.y*v4.y+v4.z*v4.z+v4.w*v4.w;
  #pragma unroll
  for (int o=1;o<64;o<<=1){ s += __shfl_xor(s,o); ss += __shfl_xor(ss,o); }
  __shared__ float red[8];
  int w = t>>6, l = t&63;
  if (l==0){ red[w]=s; red[4+w]=ss; }
  __syncthreads();
  s = red[0]+red[1]+red[2]+red[3];
  ss = red[4]+red[5]+red[6]+red[7];
  float mean = s*(1.0f/1024.0f);
  float var = ss*(1.0f/1024.0f) - mean*mean;
  float rstd = rsqrtf(var + 1e-5f);
  float4 gv = ((const float4*)gam)[t], bv = ((const float4*)bet)[t];
  float4 o;
  o.x = (v4.x-mean)*rstd*gv.x + bv.x;
  o.y = (v4.y-mean)*rstd*gv.y + bv.y;
  o.z = (v4.z-mean)*rstd*gv.z + bv.z;
  o.w = (v4.w-mean)*rstd*gv.w + bv.w;
  ((float4*)(out + (size_t)row*1024))[t] = o;
}

extern "C" void kernel_launch(void* const* d_in, const int* in_sizes, int n_in,
                              void* d_out, int out_size, void* d_ws, size_t ws_size,
                              hipStream_t stream) {
  const float* x     = (const float*)d_in[0];
  const float* Wq    = (const float*)d_in[1];
  const float* Wk    = (const float*)d_in[2];
  const float* Wv    = (const float*)d_in[3];
  const float* Wo    = (const float*)d_in[4];
  const float* lq1   = (const float*)d_in[5];
  const float* lk1   = (const float*)d_in[6];
  const float* lq2   = (const float*)d_in[7];
  const float* lk2   = (const float*)d_in[8];
  const float* gamma = (const float*)d_in[9];
  const float* beta  = (const float*)d_in[10];
  float* out = (float*)d_out;

  char* ws = (char*)d_ws;
  unsigned short* xb    = (unsigned short*)(ws);                   //  8,388,608 B
  unsigned short* WcatT = (unsigned short*)(ws + 8388608);         // 10,485,760  [5120][1024]
  unsigned short* WoT   = (unsigned short*)(ws + 18874368);        //  2,097,152
  unsigned short* QKV   = (unsigned short*)(ws + 20971520);        // 41,943,040  [4096][5120] (V region unused)
  unsigned short* Vtb   = (unsigned short*)(ws + 62914560);        //  8,388,608  [1024][4096]
  unsigned short* AO1   = (unsigned short*)(ws + 71303168);        //  8,388,608
  unsigned short* AO2   = (unsigned short*)(ws + 79691776);        //  8,388,608
  float*          proj  = (float*)(ws + 20971520);                 // aliases QKV (dead after diff_attn)
  float*          lambp = (float*)(ws + 96468992);                 //  4

  const float QSCALE = 0.125f * 1.4426950408889634f;  // folded into Wq
  prep_k<<<10241, 256, 0, stream>>>(x, xb, Wq, Wk, Wv, Wo, WcatT, WoT, QSCALE,
                                    lq1, lk1, lq2, lk2, lambp);

  // fused QKV projection; V columns written directly transposed to Vtb
  gemm_qkv<<<dim3(32,40), 256, 0, stream>>>(xb, WcatT, QKV, Vtb, 4096, 5120, 1024);

  // stream-split attention: z = s*2 + b; stream 1 writes -lambda * O2
  diff_attn<<<dim3(16,16,4), 256, 0, stream>>>(QKV, QKV + 2048, Vtb, lambp, AO1, AO2);

  // Wo projection with fused combine: (AO1 + AO2) @ WoT
  gemm_wo_fused<<<dim3(64,8), 256, 0, stream>>>(AO1, AO2, WoT, proj, 4096, 1024, 1024);
  ln_k<<<4096, 256, 0, stream>>>(proj, gamma, beta, out);
}